// Round 7
// baseline (610.937 us; speedup 1.0000x reference)
//
#include <hip/hip_runtime.h>
#include <hip/hip_fp16.h>

// N=50000 nodes, E=850000 edges, H=8 heads, D=32, H*D=256, IN=128, SM=256, SP=128

typedef unsigned int uint32;
typedef unsigned short u16;
typedef short short8 __attribute__((ext_vector_type(8)));
typedef float f32x4 __attribute__((ext_vector_type(4)));
typedef _Float16 f16x2 __attribute__((ext_vector_type(2)));

union H2 { f16x2 v; uint32 u; };

// fp32 -> bf16 round-to-nearest-even (low 16 bits)
__device__ __forceinline__ uint32 bf_rne(uint32 u) { return (u + 0x7fffu + ((u >> 16) & 1u)) >> 16; }

// cheap split: hi = trunc-bf16(a), lo = trunc-bf16(a - hi); packed pairs via v_perm
__device__ __forceinline__ void split_trunc(float a, float b, uint32& h, uint32& l) {
  uint32 ua = __float_as_uint(a), ub = __float_as_uint(b);
  h = __builtin_amdgcn_perm(ub, ua, 0x07060302u);  // [ub.hi16 | ua.hi16]
  float ra = a - __uint_as_float(ua & 0xffff0000u);
  float rb = b - __uint_as_float(ub & 0xffff0000u);
  l = __builtin_amdgcn_perm(__float_as_uint(rb), __float_as_uint(ra), 0x07060302u);
}

__device__ __forceinline__ int wave_incl_scan(int x) {
  int lane = threadIdx.x & 63;
#pragma unroll
  for (int off = 1; off < 64; off <<= 1) {
    int t = __shfl_up(x, off, 64);
    if (lane >= off) x += t;
  }
  return x;
}

// ---------------- CSR build ----------------
__global__ __launch_bounds__(256) void k_deg(const int* __restrict__ dst, int* __restrict__ deg, int E) {
  int e = blockIdx.x * 256 + threadIdx.x;
  if (e < E) atomicAdd(&deg[dst[e]], 1);
}

__global__ __launch_bounds__(256) void k_blkscan(const int* __restrict__ in, int* __restrict__ out,
                                                 int* __restrict__ blksum, int n) {
  __shared__ int wsum[4];
  int tid = threadIdx.x;
  int i0 = blockIdx.x * 1024 + tid * 4;
  int v0 = 0, v1 = 0, v2 = 0, v3 = 0;
  if (i0 + 3 < n) {
    int4 t = *(const int4*)(in + i0);
    v0 = t.x; v1 = t.y; v2 = t.z; v3 = t.w;
  } else {
    if (i0 < n) v0 = in[i0];
    if (i0 + 1 < n) v1 = in[i0 + 1];
    if (i0 + 2 < n) v2 = in[i0 + 2];
    if (i0 + 3 < n) v3 = in[i0 + 3];
  }
  int ts = v0 + v1 + v2 + v3;
  int incl = wave_incl_scan(ts);
  int lane = tid & 63, wid = tid >> 6;
  if (lane == 63) wsum[wid] = incl;
  __syncthreads();
  if (tid == 0) {
    int a = wsum[0], b = wsum[1], c = wsum[2], d = wsum[3];
    wsum[0] = 0; wsum[1] = a; wsum[2] = a + b; wsum[3] = a + b + c;
    blksum[blockIdx.x] = a + b + c + d;
  }
  __syncthreads();
  int excl = wsum[wid] + incl - ts;
  if (i0 + 3 < n) {
    int4 o; o.x = excl; o.y = excl + v0; o.z = excl + v0 + v1; o.w = excl + v0 + v1 + v2;
    *(int4*)(out + i0) = o;
  } else {
    if (i0 < n) out[i0] = excl;
    if (i0 + 1 < n) out[i0 + 1] = excl + v0;
    if (i0 + 2 < n) out[i0 + 2] = excl + v0 + v1;
    if (i0 + 3 < n) out[i0 + 3] = excl + v0 + v1 + v2;
  }
}

__global__ void k_scan_top(int* __restrict__ bs, int G) {
  int lane = threadIdx.x;  // 64 threads
  int base = 0;
  for (int s = 0; s < G; s += 64) {
    int i = s + lane;
    int v = (i < G) ? bs[i] : 0;
    int incl = wave_incl_scan(v);
    if (i < G) bs[i] = base + incl - v;
    base += __shfl(incl, 63, 64);
  }
}

__global__ __launch_bounds__(256) void k_addoff(int* __restrict__ rp, const int* __restrict__ bs, int n, int Etot) {
  int i = blockIdx.x * 256 + threadIdx.x;
  if (i < n) rp[i] += bs[i >> 10];
  if (i == 0) rp[n] = Etot;
}

__global__ __launch_bounds__(256) void k_fill(const int* __restrict__ src, const int* __restrict__ dst,
                                              const int* __restrict__ rp, int* __restrict__ cnt,
                                              int* __restrict__ csr_src, int E) {
  int e = blockIdx.x * 256 + threadIdx.x;
  if (e < E) {
    int d = dst[e];
    int p = rp[d] + atomicAdd(&cnt[d], 1);
    csr_src[p] = src[e];
  }
}

// ---- combined layer-1 weights, split-bf16, stored in MFMA-fragment order ----
// Bfrag index: ((((cb*12 + kt)*8 + ni)*4 + lq)*16 + lr)*8 + j8
//   cb = col/128, kt = k/32, ni = (col%128)/16, lq = (k%32)/8, lr = col%16, j8 = k%8
__global__ __launch_bounds__(256) void k_precomb(const float* __restrict__ T1w, const float* __restrict__ T1b,
                                                 const float* __restrict__ T2w, const float* __restrict__ T2b,
                                                 const float* __restrict__ G, u16* __restrict__ Bh,
                                                 u16* __restrict__ Bl, float* __restrict__ cvec, int off) {
  int r = blockIdx.x;   // 0..384: K index (384 rows) + 1 bias row
  int j = threadIdx.x;  // col within 256
  float acc = 0.f;
  if (r < 256) {
    for (int m = 0; m < 128; m++) acc += T1w[r * 128 + m] * G[m * 256 + j];
  } else if (r < 384) {
    int rr = r - 256;
    for (int m = 0; m < 128; m++) acc += T2w[rr * 128 + m] * G[(128 + m) * 256 + j];
  } else {
    for (int m = 0; m < 128; m++) acc += T1b[m] * G[m * 256 + j] + T2b[m] * G[(128 + m) * 256 + j];
    cvec[off + j] = acc;
    return;
  }
  uint32 u = __float_as_uint(acc);
  uint32 hi = bf_rne(u);
  float rest = acc - __uint_as_float(hi << 16);
  uint32 lo = __float_as_uint(rest) >> 16;
  int k = r, colabs = off + j;
  int kt = k >> 5, lq = (k >> 3) & 3, j8 = k & 7;
  int cb = colabs >> 7, colr = colabs & 127, ni = colr >> 4, lr = colr & 15;
  size_t idx = ((size_t)(((cb * 12 + kt) * 8 + ni) * 4 + lq) * 16 + lr) * 8 + j8;
  Bh[idx] = (u16)hi;
  Bl[idx] = (u16)lo;
}

// ---- split-bf16 MFMA GEMM: C[N,512] = [sm|sp][N,384] @ Wc[384,512] + cvec; outputs fp16 ----
// 128x128 block, 6 K-stages of 64; B staged identity-mapped (coalesced global, zero-conflict LDS);
// A per-lane direct from global, split in-register. 32 KB LDS -> 4 blocks/CU.
__global__ __launch_bounds__(256, 4) void k_gemm(const float* __restrict__ sm, const float* __restrict__ sp,
                                                 const u16* __restrict__ Bth, const u16* __restrict__ Btl,
                                                 const float* __restrict__ cvec, __half* __restrict__ fs,
                                                 __half* __restrict__ fd, int N) {
  __shared__ u16 BH[8192];  // 16 KB: 2 k-tiles x 8 ni x 64 lanes x 8 halves
  __shared__ u16 BL[8192];
  int tid = threadIdx.x, w = tid >> 6, l = tid & 63;
  int lr = l & 15, lq = l >> 4;
  int cb = blockIdx.x, col0 = cb * 128, row0 = blockIdx.y * 128;
  int r0 = row0 + w * 32 + lr;
  int r1 = r0 + 16;
  int c0 = r0 < N ? r0 : N - 1;
  int c1 = r1 < N ? r1 : N - 1;

  f32x4 acc[2][8];
#pragma unroll
  for (int mt = 0; mt < 2; mt++)
#pragma unroll
    for (int ni = 0; ni < 8; ni++) acc[mt][ni] = (f32x4){0.f, 0.f, 0.f, 0.f};

  for (int st = 0; st < 6; st++) {
    int koff = st * 64;
    size_t g0 = (size_t)(cb * 12 + st * 2) * 4096;  // halfword offset of this stage's 2 k-tiles
    if (st) __syncthreads();
#pragma unroll
    for (int i = 0; i < 4; i++) {
      int c = i * 256 + tid;  // 16B chunk index, identity map global->LDS
      *(uint4*)&BH[c * 8] = *(const uint4*)(Bth + g0 + c * 8);
      *(uint4*)&BL[c * 8] = *(const uint4*)(Btl + g0 + c * 8);
    }
    __syncthreads();
#pragma unroll
    for (int t = 0; t < 2; t++) {
      int kk = koff + t * 32;
      int ks = kk + lq * 8;
      const float* ga0 = (kk < 256) ? (sm + (size_t)c0 * 256 + ks) : (sp + (size_t)c0 * 128 + (ks - 256));
      const float* ga1 = (kk < 256) ? (sm + (size_t)c1 * 256 + ks) : (sp + (size_t)c1 * 128 + (ks - 256));
      float4 v00 = *(const float4*)(ga0);
      float4 v01 = *(const float4*)(ga0 + 4);
      float4 v10 = *(const float4*)(ga1);
      float4 v11 = *(const float4*)(ga1 + 4);
      uint4 H0, L0, H1, L1;
      split_trunc(v00.x, v00.y, H0.x, L0.x);
      split_trunc(v00.z, v00.w, H0.y, L0.y);
      split_trunc(v01.x, v01.y, H0.z, L0.z);
      split_trunc(v01.z, v01.w, H0.w, L0.w);
      split_trunc(v10.x, v10.y, H1.x, L1.x);
      split_trunc(v10.z, v10.w, H1.y, L1.y);
      split_trunc(v11.x, v11.y, H1.z, L1.z);
      split_trunc(v11.z, v11.w, H1.w, L1.w);
      short8 a0h = *(short8*)&H0, a0l = *(short8*)&L0;
      short8 a1h = *(short8*)&H1, a1l = *(short8*)&L1;
#pragma unroll
      for (int ni = 0; ni < 8; ni++) {
        int lo = ((t * 8 + ni) * 64 + l) * 8;  // lane-contiguous: zero bank conflicts
        short8 bh = *(const short8*)&BH[lo];
        short8 bl = *(const short8*)&BL[lo];
        acc[0][ni] = __builtin_amdgcn_mfma_f32_16x16x32_bf16(a0h, bh, acc[0][ni], 0, 0, 0);
        acc[0][ni] = __builtin_amdgcn_mfma_f32_16x16x32_bf16(a0l, bh, acc[0][ni], 0, 0, 0);
        acc[0][ni] = __builtin_amdgcn_mfma_f32_16x16x32_bf16(a0h, bl, acc[0][ni], 0, 0, 0);
        acc[1][ni] = __builtin_amdgcn_mfma_f32_16x16x32_bf16(a1h, bh, acc[1][ni], 0, 0, 0);
        acc[1][ni] = __builtin_amdgcn_mfma_f32_16x16x32_bf16(a1l, bh, acc[1][ni], 0, 0, 0);
        acc[1][ni] = __builtin_amdgcn_mfma_f32_16x16x32_bf16(a1h, bl, acc[1][ni], 0, 0, 0);
      }
    }
  }
  // epilogue: C row = lq*4 + reg, col = lane&15 per 16x16 tile; store fp16
#pragma unroll
  for (int mt = 0; mt < 2; mt++) {
    int rb = row0 + w * 32 + mt * 16 + lq * 4;
#pragma unroll
    for (int ni = 0; ni < 8; ni++) {
      int c = col0 + ni * 16 + lr;
      float cv = cvec[c];
      __half* op = fs; int cc = c;
      if (c >= 256) { op = fd; cc = c - 256; }
#pragma unroll
      for (int r = 0; r < 4; r++) {
        int rr = rb + r;
        if (rr < N) op[(size_t)rr * 256 + cc] = __float2half(acc[mt][ni][r] + cv);
      }
    }
  }
}

// ---- layer-2 feature GEMM: fs/fd[N,256] = h[N,32] @ W[32,256]; b128 LDS reads, 8 FMA/read ----
__global__ __launch_bounds__(256) void k_feat2(const float* __restrict__ h, const float* __restrict__ Ws,
                                               const float* __restrict__ Wd, __half* __restrict__ fs,
                                               __half* __restrict__ fd, int N) {
  __shared__ float hs[16][32];
  int tid = threadIdx.x;
  int n0 = blockIdx.x * 16;
  if (n0 + 16 <= N) {
    if (tid < 128) ((float4*)hs)[tid] = ((const float4*)(h + (size_t)n0 * 32))[tid];
  } else {
    for (int i = tid; i < 512; i += 256) {
      int nn = i >> 5, k = i & 31;
      int n = n0 + nn;
      hs[nn][k] = (n < N) ? h[n * 32 + k] : 0.f;
    }
  }
  __syncthreads();
  float accs[16] = {}, accd[16] = {};
  int j = tid;
#pragma unroll
  for (int k0 = 0; k0 < 32; k0 += 4) {
    float4 ws = {Ws[(k0 + 0) * 256 + j], Ws[(k0 + 1) * 256 + j], Ws[(k0 + 2) * 256 + j], Ws[(k0 + 3) * 256 + j]};
    float4 wd = {Wd[(k0 + 0) * 256 + j], Wd[(k0 + 1) * 256 + j], Wd[(k0 + 2) * 256 + j], Wd[(k0 + 3) * 256 + j]};
#pragma unroll
    for (int nn = 0; nn < 16; nn++) {
      float4 hv = *(const float4*)&hs[nn][k0];  // b128 broadcast: 8 FMA per LDS read
      accs[nn] += hv.x * ws.x + hv.y * ws.y + hv.z * ws.z + hv.w * ws.w;
      accd[nn] += hv.x * wd.x + hv.y * wd.y + hv.z * wd.z + hv.w * wd.w;
    }
  }
#pragma unroll
  for (int nn = 0; nn < 16; nn++) {
    int n = n0 + nn;
    if (n < N) {
      fs[(size_t)n * 256 + j] = __float2half(accs[nn]);
      fd[(size_t)n * 256 + j] = __float2half(accd[nn]);
    }
  }
}

// ---- fused edge pass, packed-fp16 math: per-dst softmax + aggregate + bias (+elu) + head-mean ----
// one wave per dst node; lane L holds feature elements 4L..4L+3 (head = L>>3)
template <int FINAL>
__global__ __launch_bounds__(256) void k_edge(const uint2* __restrict__ fs, const uint2* __restrict__ fd,
                                              const int* __restrict__ csr_src, const int* __restrict__ rp,
                                              const float* __restrict__ attn, const float* __restrict__ bias,
                                              float* __restrict__ out, int N) {
  int n = blockIdx.x * 4 + (threadIdx.x >> 6);
  if (n >= N) return;
  int lane = threadIdx.x & 63;
  float4 av = ((const float4*)attn)[lane];
  H2 AV01, AV23, Y01, Y23;
  AV01.v = (f16x2){(_Float16)av.x, (_Float16)av.y};
  AV23.v = (f16x2){(_Float16)av.z, (_Float16)av.w};
  const f16x2 c02 = {(_Float16)0.2f, (_Float16)0.2f};
  uint2 yu = fd[(size_t)n * 64 + lane];
  Y01.u = yu.x; Y23.u = yu.y;
  int beg = rp[n], end = rp[n + 1];
  float den = 0.f;
  float4 acc = {0.f, 0.f, 0.f, 0.f};
  int s = (beg < end) ? csr_src[beg] : 0;
  for (int e = beg; e < end; e++) {
    int snext = (e + 1 < end) ? csr_src[e + 1] : 0;
    uint2 xu = fs[(size_t)s * 64 + lane];
    H2 X01, X23; X01.u = xu.x; X23.u = xu.y;
    f16x2 e01 = X01.v + Y01.v;                       // v_pk_add_f16
    f16x2 e23 = X23.v + Y23.v;
    f16x2 t01 = __builtin_elementwise_max(e01, e01 * c02);  // v_pk_max/mul_f16: leaky-relu
    f16x2 t23 = __builtin_elementwise_max(e23, e23 * c02);
    float p = __builtin_amdgcn_fdot2(t01, AV01.v, 0.f, false);
    p = __builtin_amdgcn_fdot2(t23, AV23.v, p, false);
    p += __shfl_xor(p, 1, 64);
    p += __shfl_xor(p, 2, 64);
    p += __shfl_xor(p, 4, 64);  // all 8 lanes of this head hold the head score
    float wgt = __expf(p);      // scores bounded: exp-safe without max shift
    den += wgt;
    acc.x += wgt * (float)X01.v.x;
    acc.y += wgt * (float)X01.v.y;
    acc.z += wgt * (float)X23.v.x;
    acc.w += wgt * (float)X23.v.y;
    s = snext;
  }
  float invd = 1.f / den;
  float4 b = ((const float4*)bias)[lane];
  acc.x = acc.x * invd + b.x;
  acc.y = acc.y * invd + b.y;
  acc.z = acc.z * invd + b.z;
  acc.w = acc.w * invd + b.w;
  if (!FINAL) {
    acc.x = acc.x > 0.f ? acc.x : expm1f(acc.x);
    acc.y = acc.y > 0.f ? acc.y : expm1f(acc.y);
    acc.z = acc.z > 0.f ? acc.z : expm1f(acc.z);
    acc.w = acc.w > 0.f ? acc.w : expm1f(acc.w);
  }
#pragma unroll
  for (int mask = 8; mask <= 32; mask <<= 1) {
    acc.x += __shfl_xor(acc.x, mask, 64);
    acc.y += __shfl_xor(acc.y, mask, 64);
    acc.z += __shfl_xor(acc.z, mask, 64);
    acc.w += __shfl_xor(acc.w, mask, 64);
  }
  if (lane < 8) {
    float4 o = {acc.x * 0.125f, acc.y * 0.125f, acc.z * 0.125f, acc.w * 0.125f};
    ((float4*)out)[(size_t)n * 8 + lane] = o;
  }
}

extern "C" void kernel_launch(void* const* d_in, const int* in_sizes, int n_in,
                              void* d_out, int out_size, void* d_ws, size_t ws_size,
                              hipStream_t stream) {
  const float* sm  = (const float*)d_in[0];
  const float* sp  = (const float*)d_in[1];
  const int*   src = (const int*)d_in[2];
  const int*   dst = (const int*)d_in[3];
  const float* T1w = (const float*)d_in[4];
  const float* T1b = (const float*)d_in[5];
  const float* T2w = (const float*)d_in[6];
  const float* T2b = (const float*)d_in[7];
  const float* g1sw = (const float*)d_in[8];
  const float* g1dw = (const float*)d_in[9];
  const float* g1a  = (const float*)d_in[10];
  const float* g1b  = (const float*)d_in[11];
  const float* g2sw = (const float*)d_in[12];
  const float* g2dw = (const float*)d_in[13];
  const float* g2a  = (const float*)d_in[14];
  const float* g2b  = (const float*)d_in[15];
  const int N = in_sizes[1] / 128;  // sp_feats is [N,128]
  const int E = in_sizes[2];
  float* out = (float*)d_out;

  size_t off = 0;
  char* wsb = (char*)d_ws;
  auto alloc = [&](size_t bytes) -> void* {
    void* p = wsb + off;
    off += (bytes + 255) & ~(size_t)255;
    return p;
  };
  u16* Bth = (u16*)alloc((size_t)512 * 384 * 2);
  u16* Btl = (u16*)alloc((size_t)512 * 384 * 2);
  float* cvec  = (float*)alloc(512 * 4);
  int* deg     = (int*)alloc((size_t)N * 4);
  int* cnt     = (int*)alloc((size_t)N * 4);
  int* row_ptr = (int*)alloc((size_t)(N + 1) * 4);
  int* blksum  = (int*)alloc(4096 * 4);
  int* csr_src = (int*)alloc((size_t)E * 4);
  __half* fs   = (__half*)alloc((size_t)N * 256 * 2);
  __half* fd   = (__half*)alloc((size_t)N * 256 * 2);
  float* hmid  = (float*)alloc((size_t)N * 32 * 4);
  (void)ws_size; (void)n_in; (void)out_size;

  (void)hipMemsetAsync(deg, 0, (size_t)N * 4, stream);
  (void)hipMemsetAsync(cnt, 0, (size_t)N * 4, stream);

  // CSR by destination (shared by both layers)
  k_deg<<<(E + 255) / 256, 256, 0, stream>>>(dst, deg, E);
  int nblk = (N + 1023) / 1024;
  k_blkscan<<<nblk, 256, 0, stream>>>(deg, row_ptr, blksum, N);
  k_scan_top<<<1, 64, 0, stream>>>(blksum, nblk);
  k_addoff<<<(N + 255) / 256, 256, 0, stream>>>(row_ptr, blksum, N, E);
  k_fill<<<(E + 255) / 256, 256, 0, stream>>>(src, dst, row_ptr, cnt, csr_src, E);

  // fold T1/T2 into layer-1 weights, split-bf16, fragment-ordered
  k_precomb<<<385, 256, 0, stream>>>(T1w, T1b, T2w, T2b, g1sw, Bth, Btl, cvec, 0);
  k_precomb<<<385, 256, 0, stream>>>(T1w, T1b, T2w, T2b, g1dw, Bth, Btl, cvec, 256);

  // layer 1
  dim3 ggrid(4, (N + 127) / 128);
  k_gemm<<<ggrid, 256, 0, stream>>>(sm, sp, Bth, Btl, cvec, fs, fd, N);
  k_edge<0><<<(N + 3) / 4, 256, 0, stream>>>((const uint2*)fs, (const uint2*)fd, csr_src, row_ptr, g1a, g1b, hmid, N);

  // layer 2
  k_feat2<<<(N + 15) / 16, 256, 0, stream>>>(hmid, g2sw, g2dw, fs, fd, N);
  k_edge<1><<<(N + 3) / 4, 256, 0, stream>>>((const uint2*)fs, (const uint2*)fd, csr_src, row_ptr, g2a, g2b, out, N);
}

// Round 8
// 509.167 us; speedup vs baseline: 1.1999x; 1.1999x over previous
//
#include <hip/hip_runtime.h>
#include <hip/hip_fp16.h>

// N=50000 nodes, E=850000 edges, H=8 heads, D=32, H*D=256, IN=128, SM=256, SP=128

typedef unsigned int uint32;
typedef unsigned short u16;
typedef short short8 __attribute__((ext_vector_type(8)));
typedef float f32x4 __attribute__((ext_vector_type(4)));
typedef _Float16 f16x2 __attribute__((ext_vector_type(2)));

union H2 { f16x2 v; uint32 u; };

// fp32 -> bf16 round-to-nearest-even (low 16 bits)
__device__ __forceinline__ uint32 bf_rne(uint32 u) { return (u + 0x7fffu + ((u >> 16) & 1u)) >> 16; }

// cheap split: hi = trunc-bf16(a), lo = trunc-bf16(a - hi); packed pairs via v_perm
__device__ __forceinline__ void split_trunc(float a, float b, uint32& h, uint32& l) {
  uint32 ua = __float_as_uint(a), ub = __float_as_uint(b);
  h = __builtin_amdgcn_perm(ub, ua, 0x07060302u);  // [ub.hi16 | ua.hi16]
  float ra = a - __uint_as_float(ua & 0xffff0000u);
  float rb = b - __uint_as_float(ub & 0xffff0000u);
  l = __builtin_amdgcn_perm(__float_as_uint(rb), __float_as_uint(ra), 0x07060302u);
}

__device__ __forceinline__ int wave_incl_scan(int x) {
  int lane = threadIdx.x & 63;
#pragma unroll
  for (int off = 1; off < 64; off <<= 1) {
    int t = __shfl_up(x, off, 64);
    if (lane >= off) x += t;
  }
  return x;
}

// ---------------- CSR build ----------------
__global__ __launch_bounds__(256) void k_deg(const int* __restrict__ dst, int* __restrict__ deg, int E) {
  int e = blockIdx.x * 256 + threadIdx.x;
  if (e < E) atomicAdd(&deg[dst[e]], 1);
}

__global__ __launch_bounds__(256) void k_blkscan(const int* __restrict__ in, int* __restrict__ out,
                                                 int* __restrict__ blksum, int n) {
  __shared__ int wsum[4];
  int tid = threadIdx.x;
  int i0 = blockIdx.x * 1024 + tid * 4;
  int v0 = 0, v1 = 0, v2 = 0, v3 = 0;
  if (i0 + 3 < n) {
    int4 t = *(const int4*)(in + i0);
    v0 = t.x; v1 = t.y; v2 = t.z; v3 = t.w;
  } else {
    if (i0 < n) v0 = in[i0];
    if (i0 + 1 < n) v1 = in[i0 + 1];
    if (i0 + 2 < n) v2 = in[i0 + 2];
    if (i0 + 3 < n) v3 = in[i0 + 3];
  }
  int ts = v0 + v1 + v2 + v3;
  int incl = wave_incl_scan(ts);
  int lane = tid & 63, wid = tid >> 6;
  if (lane == 63) wsum[wid] = incl;
  __syncthreads();
  if (tid == 0) {
    int a = wsum[0], b = wsum[1], c = wsum[2], d = wsum[3];
    wsum[0] = 0; wsum[1] = a; wsum[2] = a + b; wsum[3] = a + b + c;
    blksum[blockIdx.x] = a + b + c + d;
  }
  __syncthreads();
  int excl = wsum[wid] + incl - ts;
  if (i0 + 3 < n) {
    int4 o; o.x = excl; o.y = excl + v0; o.z = excl + v0 + v1; o.w = excl + v0 + v1 + v2;
    *(int4*)(out + i0) = o;
  } else {
    if (i0 < n) out[i0] = excl;
    if (i0 + 1 < n) out[i0 + 1] = excl + v0;
    if (i0 + 2 < n) out[i0 + 2] = excl + v0 + v1;
    if (i0 + 3 < n) out[i0 + 3] = excl + v0 + v1 + v2;
  }
}

__global__ void k_scan_top(int* __restrict__ bs, int G) {
  int lane = threadIdx.x;  // 64 threads
  int base = 0;
  for (int s = 0; s < G; s += 64) {
    int i = s + lane;
    int v = (i < G) ? bs[i] : 0;
    int incl = wave_incl_scan(v);
    if (i < G) bs[i] = base + incl - v;
    base += __shfl(incl, 63, 64);
  }
}

__global__ __launch_bounds__(256) void k_addoff(int* __restrict__ rp, const int* __restrict__ bs, int n, int Etot) {
  int i = blockIdx.x * 256 + threadIdx.x;
  if (i < n) rp[i] += bs[i >> 10];
  if (i == 0) rp[n] = Etot;
}

__global__ __launch_bounds__(256) void k_fill(const int* __restrict__ src, const int* __restrict__ dst,
                                              const int* __restrict__ rp, int* __restrict__ cnt,
                                              int* __restrict__ csr_src, int E) {
  int e = blockIdx.x * 256 + threadIdx.x;
  if (e < E) {
    int d = dst[e];
    int p = rp[d] + atomicAdd(&cnt[d], 1);
    csr_src[p] = src[e];
  }
}

// ---- combined layer-1 weights, split-bf16, stored in MFMA-fragment order ----
// Bfrag index: ((((cb*12 + kt)*8 + ni)*4 + lq)*16 + lr)*8 + j8
//   cb = col/128, kt = k/32, ni = (col%128)/16, lq = (k%32)/8, lr = col%16, j8 = k%8
__global__ __launch_bounds__(256) void k_precomb(const float* __restrict__ T1w, const float* __restrict__ T1b,
                                                 const float* __restrict__ T2w, const float* __restrict__ T2b,
                                                 const float* __restrict__ G, u16* __restrict__ Bh,
                                                 u16* __restrict__ Bl, float* __restrict__ cvec, int off) {
  int r = blockIdx.x;   // 0..384: K index (384 rows) + 1 bias row
  int j = threadIdx.x;  // col within 256
  float acc = 0.f;
  if (r < 256) {
    for (int m = 0; m < 128; m++) acc += T1w[r * 128 + m] * G[m * 256 + j];
  } else if (r < 384) {
    int rr = r - 256;
    for (int m = 0; m < 128; m++) acc += T2w[rr * 128 + m] * G[(128 + m) * 256 + j];
  } else {
    for (int m = 0; m < 128; m++) acc += T1b[m] * G[m * 256 + j] + T2b[m] * G[(128 + m) * 256 + j];
    cvec[off + j] = acc;
    return;
  }
  uint32 u = __float_as_uint(acc);
  uint32 hi = bf_rne(u);
  float rest = acc - __uint_as_float(hi << 16);
  uint32 lo = __float_as_uint(rest) >> 16;
  int k = r, colabs = off + j;
  int kt = k >> 5, lq = (k >> 3) & 3, j8 = k & 7;
  int cb = colabs >> 7, colr = colabs & 127, ni = colr >> 4, lr = colr & 15;
  size_t idx = ((size_t)(((cb * 12 + kt) * 8 + ni) * 4 + lq) * 16 + lr) * 8 + j8;
  Bh[idx] = (u16)hi;
  Bl[idx] = (u16)lo;
}

// ---- split-bf16 MFMA GEMM: C[N,512] = [sm|sp][N,384] @ Wc[384,512] + cvec; outputs fp16 ----
// 128x128 block, 6 K-stages of 64; B staged identity-mapped (coalesced global, zero-conflict LDS);
// A per-lane direct from global, split in-register. 32 KB LDS -> 4 blocks/CU.
__global__ __launch_bounds__(256, 4) void k_gemm(const float* __restrict__ sm, const float* __restrict__ sp,
                                                 const u16* __restrict__ Bth, const u16* __restrict__ Btl,
                                                 const float* __restrict__ cvec, __half* __restrict__ fs,
                                                 __half* __restrict__ fd, int N) {
  __shared__ u16 BH[8192];  // 16 KB: 2 k-tiles x 8 ni x 64 lanes x 8 halves
  __shared__ u16 BL[8192];
  int tid = threadIdx.x, w = tid >> 6, l = tid & 63;
  int lr = l & 15, lq = l >> 4;
  int cb = blockIdx.x, col0 = cb * 128, row0 = blockIdx.y * 128;
  int r0 = row0 + w * 32 + lr;
  int r1 = r0 + 16;
  int c0 = r0 < N ? r0 : N - 1;
  int c1 = r1 < N ? r1 : N - 1;

  f32x4 acc[2][8];
#pragma unroll
  for (int mt = 0; mt < 2; mt++)
#pragma unroll
    for (int ni = 0; ni < 8; ni++) acc[mt][ni] = (f32x4){0.f, 0.f, 0.f, 0.f};

  for (int st = 0; st < 6; st++) {
    int koff = st * 64;
    size_t g0 = (size_t)(cb * 12 + st * 2) * 4096;  // halfword offset of this stage's 2 k-tiles
    if (st) __syncthreads();
#pragma unroll
    for (int i = 0; i < 4; i++) {
      int c = i * 256 + tid;  // 16B chunk index, identity map global->LDS
      *(uint4*)&BH[c * 8] = *(const uint4*)(Bth + g0 + c * 8);
      *(uint4*)&BL[c * 8] = *(const uint4*)(Btl + g0 + c * 8);
    }
    __syncthreads();
#pragma unroll
    for (int t = 0; t < 2; t++) {
      int kk = koff + t * 32;
      int ks = kk + lq * 8;
      const float* ga0 = (kk < 256) ? (sm + (size_t)c0 * 256 + ks) : (sp + (size_t)c0 * 128 + (ks - 256));
      const float* ga1 = (kk < 256) ? (sm + (size_t)c1 * 256 + ks) : (sp + (size_t)c1 * 128 + (ks - 256));
      float4 v00 = *(const float4*)(ga0);
      float4 v01 = *(const float4*)(ga0 + 4);
      float4 v10 = *(const float4*)(ga1);
      float4 v11 = *(const float4*)(ga1 + 4);
      uint4 H0, L0, H1, L1;
      split_trunc(v00.x, v00.y, H0.x, L0.x);
      split_trunc(v00.z, v00.w, H0.y, L0.y);
      split_trunc(v01.x, v01.y, H0.z, L0.z);
      split_trunc(v01.z, v01.w, H0.w, L0.w);
      split_trunc(v10.x, v10.y, H1.x, L1.x);
      split_trunc(v10.z, v10.w, H1.y, L1.y);
      split_trunc(v11.x, v11.y, H1.z, L1.z);
      split_trunc(v11.z, v11.w, H1.w, L1.w);
      short8 a0h = *(short8*)&H0, a0l = *(short8*)&L0;
      short8 a1h = *(short8*)&H1, a1l = *(short8*)&L1;
#pragma unroll
      for (int ni = 0; ni < 8; ni++) {
        int lo = ((t * 8 + ni) * 64 + l) * 8;  // lane-contiguous: zero bank conflicts
        short8 bh = *(const short8*)&BH[lo];
        short8 bl = *(const short8*)&BL[lo];
        acc[0][ni] = __builtin_amdgcn_mfma_f32_16x16x32_bf16(a0h, bh, acc[0][ni], 0, 0, 0);
        acc[0][ni] = __builtin_amdgcn_mfma_f32_16x16x32_bf16(a0l, bh, acc[0][ni], 0, 0, 0);
        acc[0][ni] = __builtin_amdgcn_mfma_f32_16x16x32_bf16(a0h, bl, acc[0][ni], 0, 0, 0);
        acc[1][ni] = __builtin_amdgcn_mfma_f32_16x16x32_bf16(a1h, bh, acc[1][ni], 0, 0, 0);
        acc[1][ni] = __builtin_amdgcn_mfma_f32_16x16x32_bf16(a1l, bh, acc[1][ni], 0, 0, 0);
        acc[1][ni] = __builtin_amdgcn_mfma_f32_16x16x32_bf16(a1h, bl, acc[1][ni], 0, 0, 0);
      }
    }
  }
  // epilogue: C row = lq*4 + reg, col = lane&15 per 16x16 tile; store fp16
#pragma unroll
  for (int mt = 0; mt < 2; mt++) {
    int rb = row0 + w * 32 + mt * 16 + lq * 4;
#pragma unroll
    for (int ni = 0; ni < 8; ni++) {
      int c = col0 + ni * 16 + lr;
      float cv = cvec[c];
      __half* op = fs; int cc = c;
      if (c >= 256) { op = fd; cc = c - 256; }
#pragma unroll
      for (int r = 0; r < 4; r++) {
        int rr = rb + r;
        if (rr < N) op[(size_t)rr * 256 + cc] = __float2half(acc[mt][ni][r] + cv);
      }
    }
  }
}

// ---- layer-2 feature GEMM: fs/fd[N,256] = h[N,32] @ W[32,256] ----
// thread j owns column j; W columns pinned in 64 VGPRs; h rows via wave-uniform scalar loads.
// No LDS, no spill (VGPR ~90), stores coalesced fp16.
__global__ __launch_bounds__(256) void k_feat2(const float* __restrict__ h, const float* __restrict__ Ws,
                                               const float* __restrict__ Wd, __half* __restrict__ fs,
                                               __half* __restrict__ fd, int N) {
  int j = threadIdx.x;
  int n0 = blockIdx.x * 32;
  float ws[32], wd[32];
#pragma unroll
  for (int k = 0; k < 32; k++) {
    ws[k] = Ws[k * 256 + j];
    wd[k] = Wd[k * 256 + j];
  }
  int nend = n0 + 32; if (nend > N) nend = N;
#pragma unroll 2
  for (int n = n0; n < nend; n++) {
    const float* hr = h + (size_t)n * 32;  // wave-uniform -> scalar loads
    float as = 0.f, ad = 0.f;
#pragma unroll
    for (int k = 0; k < 32; k++) {
      float hv = hr[k];
      as += hv * ws[k];
      ad += hv * wd[k];
    }
    fs[(size_t)n * 256 + j] = __float2half(as);
    fd[(size_t)n * 256 + j] = __float2half(ad);
  }
}

// ---- fused edge pass, packed-fp16 math, 2-edge ILP: per-dst softmax + aggregate + bias (+elu) + head-mean ----
// one wave per dst node; lane L holds feature elements 4L..4L+3 (head = L>>3)
template <int FINAL>
__global__ __launch_bounds__(256) void k_edge(const uint2* __restrict__ fs, const uint2* __restrict__ fd,
                                              const int* __restrict__ csr_src, const int* __restrict__ rp,
                                              const float* __restrict__ attn, const float* __restrict__ bias,
                                              float* __restrict__ out, int N) {
  int n = blockIdx.x * 4 + (threadIdx.x >> 6);
  if (n >= N) return;
  int lane = threadIdx.x & 63;
  float4 av = ((const float4*)attn)[lane];
  H2 AV01, AV23, Y01, Y23;
  AV01.v = (f16x2){(_Float16)av.x, (_Float16)av.y};
  AV23.v = (f16x2){(_Float16)av.z, (_Float16)av.w};
  const f16x2 c02 = {(_Float16)0.2f, (_Float16)0.2f};
  uint2 yu = fd[(size_t)n * 64 + lane];
  Y01.u = yu.x; Y23.u = yu.y;
  int beg = rp[n], end = rp[n + 1];
  float den0 = 0.f, den1 = 0.f;
  float4 acc0 = {0.f, 0.f, 0.f, 0.f}, acc1 = {0.f, 0.f, 0.f, 0.f};
  int e = beg;
  for (; e + 2 <= end; e += 2) {
    int s0 = csr_src[e], s1 = csr_src[e + 1];  // wave-uniform scalar loads
    uint2 xu0 = fs[(size_t)s0 * 64 + lane];    // two gathers in flight
    uint2 xu1 = fs[(size_t)s1 * 64 + lane];
    H2 Xa, Xb, Xc, Xd;
    Xa.u = xu0.x; Xb.u = xu0.y; Xc.u = xu1.x; Xd.u = xu1.y;
    f16x2 ea0 = Xa.v + Y01.v, eb0 = Xb.v + Y23.v;
    f16x2 ea1 = Xc.v + Y01.v, eb1 = Xd.v + Y23.v;
    f16x2 ta0 = __builtin_elementwise_max(ea0, ea0 * c02);
    f16x2 tb0 = __builtin_elementwise_max(eb0, eb0 * c02);
    f16x2 ta1 = __builtin_elementwise_max(ea1, ea1 * c02);
    f16x2 tb1 = __builtin_elementwise_max(eb1, eb1 * c02);
    float p0 = __builtin_amdgcn_fdot2(ta0, AV01.v, 0.f, false);
    float p1 = __builtin_amdgcn_fdot2(ta1, AV01.v, 0.f, false);
    p0 = __builtin_amdgcn_fdot2(tb0, AV23.v, p0, false);
    p1 = __builtin_amdgcn_fdot2(tb1, AV23.v, p1, false);
    p0 += __shfl_xor(p0, 1, 64); p1 += __shfl_xor(p1, 1, 64);
    p0 += __shfl_xor(p0, 2, 64); p1 += __shfl_xor(p1, 2, 64);
    p0 += __shfl_xor(p0, 4, 64); p1 += __shfl_xor(p1, 4, 64);
    float w0 = __expf(p0), w1 = __expf(p1);  // scores bounded: exp-safe without max shift
    den0 += w0; den1 += w1;
    acc0.x += w0 * (float)Xa.v.x; acc0.y += w0 * (float)Xa.v.y;
    acc0.z += w0 * (float)Xb.v.x; acc0.w += w0 * (float)Xb.v.y;
    acc1.x += w1 * (float)Xc.v.x; acc1.y += w1 * (float)Xc.v.y;
    acc1.z += w1 * (float)Xd.v.x; acc1.w += w1 * (float)Xd.v.y;
  }
  if (e < end) {
    int s0 = csr_src[e];
    uint2 xu0 = fs[(size_t)s0 * 64 + lane];
    H2 Xa, Xb; Xa.u = xu0.x; Xb.u = xu0.y;
    f16x2 ea0 = Xa.v + Y01.v, eb0 = Xb.v + Y23.v;
    f16x2 ta0 = __builtin_elementwise_max(ea0, ea0 * c02);
    f16x2 tb0 = __builtin_elementwise_max(eb0, eb0 * c02);
    float p0 = __builtin_amdgcn_fdot2(ta0, AV01.v, 0.f, false);
    p0 = __builtin_amdgcn_fdot2(tb0, AV23.v, p0, false);
    p0 += __shfl_xor(p0, 1, 64);
    p0 += __shfl_xor(p0, 2, 64);
    p0 += __shfl_xor(p0, 4, 64);
    float w0 = __expf(p0);
    den0 += w0;
    acc0.x += w0 * (float)Xa.v.x; acc0.y += w0 * (float)Xa.v.y;
    acc0.z += w0 * (float)Xb.v.x; acc0.w += w0 * (float)Xb.v.y;
  }
  float4 acc = {acc0.x + acc1.x, acc0.y + acc1.y, acc0.z + acc1.z, acc0.w + acc1.w};
  float invd = 1.f / (den0 + den1);
  float4 b = ((const float4*)bias)[lane];
  acc.x = acc.x * invd + b.x;
  acc.y = acc.y * invd + b.y;
  acc.z = acc.z * invd + b.z;
  acc.w = acc.w * invd + b.w;
  if (!FINAL) {
    acc.x = acc.x > 0.f ? acc.x : expm1f(acc.x);
    acc.y = acc.y > 0.f ? acc.y : expm1f(acc.y);
    acc.z = acc.z > 0.f ? acc.z : expm1f(acc.z);
    acc.w = acc.w > 0.f ? acc.w : expm1f(acc.w);
  }
#pragma unroll
  for (int mask = 8; mask <= 32; mask <<= 1) {
    acc.x += __shfl_xor(acc.x, mask, 64);
    acc.y += __shfl_xor(acc.y, mask, 64);
    acc.z += __shfl_xor(acc.z, mask, 64);
    acc.w += __shfl_xor(acc.w, mask, 64);
  }
  if (lane < 8) {
    float4 o = {acc.x * 0.125f, acc.y * 0.125f, acc.z * 0.125f, acc.w * 0.125f};
    ((float4*)out)[(size_t)n * 8 + lane] = o;
  }
}

extern "C" void kernel_launch(void* const* d_in, const int* in_sizes, int n_in,
                              void* d_out, int out_size, void* d_ws, size_t ws_size,
                              hipStream_t stream) {
  const float* sm  = (const float*)d_in[0];
  const float* sp  = (const float*)d_in[1];
  const int*   src = (const int*)d_in[2];
  const int*   dst = (const int*)d_in[3];
  const float* T1w = (const float*)d_in[4];
  const float* T1b = (const float*)d_in[5];
  const float* T2w = (const float*)d_in[6];
  const float* T2b = (const float*)d_in[7];
  const float* g1sw = (const float*)d_in[8];
  const float* g1dw = (const float*)d_in[9];
  const float* g1a  = (const float*)d_in[10];
  const float* g1b  = (const float*)d_in[11];
  const float* g2sw = (const float*)d_in[12];
  const float* g2dw = (const float*)d_in[13];
  const float* g2a  = (const float*)d_in[14];
  const float* g2b  = (const float*)d_in[15];
  const int N = in_sizes[1] / 128;  // sp_feats is [N,128]
  const int E = in_sizes[2];
  float* out = (float*)d_out;

  size_t off = 0;
  char* wsb = (char*)d_ws;
  auto alloc = [&](size_t bytes) -> void* {
    void* p = wsb + off;
    off += (bytes + 255) & ~(size_t)255;
    return p;
  };
  u16* Bth = (u16*)alloc((size_t)512 * 384 * 2);
  u16* Btl = (u16*)alloc((size_t)512 * 384 * 2);
  float* cvec  = (float*)alloc(512 * 4);
  int* deg     = (int*)alloc((size_t)N * 4);
  int* cnt     = (int*)alloc((size_t)N * 4);
  int* row_ptr = (int*)alloc((size_t)(N + 1) * 4);
  int* blksum  = (int*)alloc(4096 * 4);
  int* csr_src = (int*)alloc((size_t)E * 4);
  __half* fs   = (__half*)alloc((size_t)N * 256 * 2);
  __half* fd   = (__half*)alloc((size_t)N * 256 * 2);
  float* hmid  = (float*)alloc((size_t)N * 32 * 4);
  (void)ws_size; (void)n_in; (void)out_size;

  (void)hipMemsetAsync(deg, 0, (size_t)N * 4, stream);
  (void)hipMemsetAsync(cnt, 0, (size_t)N * 4, stream);

  // CSR by destination (shared by both layers)
  k_deg<<<(E + 255) / 256, 256, 0, stream>>>(dst, deg, E);
  int nblk = (N + 1023) / 1024;
  k_blkscan<<<nblk, 256, 0, stream>>>(deg, row_ptr, blksum, N);
  k_scan_top<<<1, 64, 0, stream>>>(blksum, nblk);
  k_addoff<<<(N + 255) / 256, 256, 0, stream>>>(row_ptr, blksum, N, E);
  k_fill<<<(E + 255) / 256, 256, 0, stream>>>(src, dst, row_ptr, cnt, csr_src, E);

  // fold T1/T2 into layer-1 weights, split-bf16, fragment-ordered
  k_precomb<<<385, 256, 0, stream>>>(T1w, T1b, T2w, T2b, g1sw, Bth, Btl, cvec, 0);
  k_precomb<<<385, 256, 0, stream>>>(T1w, T1b, T2w, T2b, g1dw, Bth, Btl, cvec, 256);

  // layer 1
  dim3 ggrid(4, (N + 127) / 128);
  k_gemm<<<ggrid, 256, 0, stream>>>(sm, sp, Bth, Btl, cvec, fs, fd, N);
  k_edge<0><<<(N + 3) / 4, 256, 0, stream>>>((const uint2*)fs, (const uint2*)fd, csr_src, row_ptr, g1a, g1b, hmid, N);

  // layer 2
  k_feat2<<<(N + 31) / 32, 256, 0, stream>>>(hmid, g2sw, g2dw, fs, fd, N);
  k_edge<1><<<(N + 3) / 4, 256, 0, stream>>>((const uint2*)fs, (const uint2*)fd, csr_src, row_ptr, g2a, g2b, out, N);
}